// Round 5
// baseline (397.905 us; speedup 1.0000x reference)
//
#include <hip/hip_runtime.h>

#define NCLS   50000
#define NC4    12500      // NCLS/4
#define BATCH  128
#define PPARTS 6
#define NROWS  768        // PPARTS*BATCH
#define FD     1536       // PPARTS*256
#define NCHUNK 5          // chunks per row (blocks per row)
#define NPART  10         // partials per row (2 waves per block)
#define WF4    1250       // float4s per wave
#define NTILE  19         // full 64-f4 tiles per wave (19*64 = 1216)
#define TAILF4 34         // 1250 - 1216
#define DEPTH  4          // LDS pipeline depth (slots)

typedef float f32x4 __attribute__((ext_vector_type(4)));

// global -> LDS async copy, 16B per lane; dest = uniform base + lane*16
#define GL2LDS(gp, lp, aux)                                                    \
  __builtin_amdgcn_global_load_lds(                                            \
      (const __attribute__((address_space(1))) void*)(gp),                     \
      (__attribute__((address_space(3))) void*)(lp), 16, 0, (aux))

__device__ __forceinline__ float wave_sum(float v) {
#pragma unroll
  for (int off = 32; off > 0; off >>= 1) v += __shfl_xor(v, off, 64);
  return v;
}

// ---------------------------------------------------------------------------
// Streaming partial CE+KL stats. Grid = NROWS*NCHUNK blocks of 128 threads;
// the two waves of a block run INDEPENDENT deep pipelines (no barriers):
// global_load_lds staging, DEPTH=4 slots, counted s_waitcnt vmcnt(6) so 6KB
// of loads stay in flight per wave for the whole loop (T3/T4 pattern).
// X is staged with NT cache policy (aux=2) so S stays L3-resident (r4 win).
// Each wave writes its own 8-float partial: {m,e1,e2,sx,ss,ssl,ssx,xl}.
// ---------------------------------------------------------------------------
__global__ __launch_bounds__(128) void chunk_k(
    const float* __restrict__ X, const float* __restrict__ S,
    const int* __restrict__ labels, float* __restrict__ P) {
  const int gid = blockIdx.x;
  const int row = gid / NCHUNK;
  const int sp  = gid - row * NCHUNK;
  const int b   = row & (BATCH - 1);
  const int t   = threadIdx.x;
  const int lane = t & 63, wid = t >> 6;
  const size_t base = (size_t)row * NCLS;
  const f32x4* xg4 = (const f32x4*)(X + base) + sp * (WF4 * 2) + wid * WF4;
  const f32x4* sg4 = (const f32x4*)(S + base) + sp * (WF4 * 2) + wid * WF4;
  const float i3 = 1.0f / 3.0f;

  __shared__ f32x4 XL[2][DEPTH][64];
  __shared__ f32x4 SL[2][DEPTH][64];

  float xl = 0.0f;
  if (sp == 0 && t == 0) xl = X[base + labels[b]];

  // online max-rescaled accumulators
  float m = -1e30f, e1 = 0.0f, e2 = 0.0f;
  float sx = 0.0f, ss = 0.0f, ssl = 0.0f, ssx = 0.0f;

  // branch-free online update of one float4 pair
  auto proc = [&](f32x4 xv, f32x4 sv) {
    const float x0 = xv.x, x1 = xv.y, x2 = xv.z, x3 = xv.w;
    const float s0 = sv.x, s1 = sv.y, s2 = sv.z, s3 = sv.w;
    const float mx = fmaxf(fmaxf(x0, x1), fmaxf(x2, x3));
    const float nm = fmaxf(m, mx);
    const float r3 = __expf((m - nm) * i3);   // exp((m-nm)/3)
    const float r  = r3 * r3 * r3;            // exp(m-nm)
    const float u0 = __expf((x0 - nm) * i3);
    const float u1 = __expf((x1 - nm) * i3);
    const float u2 = __expf((x2 - nm) * i3);
    const float u3 = __expf((x3 - nm) * i3);
    e2 = e2 * r3 + ((u0 + u1) + (u2 + u3));
    float q0 = u0 * u0, q1 = u1 * u1, q2 = u2 * u2, q3 = u3 * u3;
    e1 = e1 * r + ((q0 * u0 + q1 * u1) + (q2 * u2 + q3 * u3));
    m = nm;
    sx += ((x0 + x1) + (x2 + x3));
    ss += ((s0 + s1) + (s2 + s3));
    ssl = fmaf(s0, __logf(s0), ssl);
    ssl = fmaf(s1, __logf(s1), ssl);
    ssl = fmaf(s2, __logf(s2), ssl);
    ssl = fmaf(s3, __logf(s3), ssl);
    ssx = fmaf(s0, x0, ssx);
    ssx = fmaf(s1, x1, ssx);
    ssx = fmaf(s2, x2, ssx);
    ssx = fmaf(s3, x3, ssx);
  };

  auto stage = [&](int tile) {
    const int slot = tile & (DEPTH - 1);
    GL2LDS(xg4 + tile * 64 + lane, &XL[wid][slot][0], 2);  // NT: no L3 alloc
    GL2LDS(sg4 + tile * 64 + lane, &SL[wid][slot][0], 0);  // cached: L3-hit
  };

  auto tilecomp = [&](int slot) {
    const f32x4 xv = XL[wid][slot][lane];
    const f32x4 sv = SL[wid][slot][lane];
    proc(xv, sv);
  };

  // prologue: 3 slots in flight (6 gloads)
  stage(0); stage(1); stage(2);

  // steady state: issue slot ti+3, wait until slot ti landed (6 newer remain)
#pragma unroll 4
  for (int ti = 0; ti < NTILE - 3; ++ti) {
    asm volatile("s_waitcnt lgkmcnt(0)" ::: "memory");  // WAR: slot reuse safe
    stage(ti + 3);
    asm volatile("s_waitcnt vmcnt(6)" ::: "memory");
    __builtin_amdgcn_sched_barrier(0);
    tilecomp(ti & (DEPTH - 1));
  }
  // drain: 3 peeled iterations
  asm volatile("s_waitcnt vmcnt(4)" ::: "memory");
  __builtin_amdgcn_sched_barrier(0);
  tilecomp((NTILE - 3) & (DEPTH - 1));
  asm volatile("s_waitcnt vmcnt(2)" ::: "memory");
  __builtin_amdgcn_sched_barrier(0);
  tilecomp((NTILE - 2) & (DEPTH - 1));
  asm volatile("s_waitcnt vmcnt(0)" ::: "memory");
  __builtin_amdgcn_sched_barrier(0);
  tilecomp((NTILE - 1) & (DEPTH - 1));

  // tail: 34 float4s via register path
  if (lane < TAILF4) {
    f32x4 xv = __builtin_nontemporal_load(xg4 + NTILE * 64 + lane);
    f32x4 sv = sg4[NTILE * 64 + lane];
    proc(xv, sv);
  }

  // wave reduction with max-rescale (per wave; no cross-wave combine)
#pragma unroll
  for (int off = 32; off > 0; off >>= 1) {
    float mo  = __shfl_xor(m, off, 64);
    float e1o = __shfl_xor(e1, off, 64);
    float e2o = __shfl_xor(e2, off, 64);
    float nm = fmaxf(m, mo);
    e1 = e1 * __expf(m - nm) + e1o * __expf(mo - nm);
    e2 = e2 * __expf((m - nm) * i3) + e2o * __expf((mo - nm) * i3);
    m = nm;
    sx  += __shfl_xor(sx, off, 64);
    ss  += __shfl_xor(ss, off, 64);
    ssl += __shfl_xor(ssl, off, 64);
    ssx += __shfl_xor(ssx, off, 64);
  }

  if (lane == 0) {
    float4* o = (float4*)(P + (size_t)(row * NPART + sp * 2 + wid) * 8);
    o[0] = make_float4(m, e1, e2, sx);
    o[1] = make_float4(ss, ssl, ssx, xl);
  }
}

// ---------------------------------------------- normalize concat features
__global__ __launch_bounds__(256) void normalize_k(
    const float* __restrict__ idf, const float* __restrict__ grayf,
    float* __restrict__ Fn, float* __restrict__ Gn) {
  const int src = blockIdx.x >> 7;
  const int b = blockIdx.x & (BATCH - 1);
  const int t = threadIdx.x;
  const float* in = src ? grayf : idf;
  float* out = src ? Gn : Fn;

  float v[6];
  float sq = 0.0f;
#pragma unroll
  for (int k = 0; k < 6; ++k) {
    v[k] = in[((k * BATCH + b) << 8) + t];
    sq = fmaf(v[k], v[k], sq);
  }
  sq = wave_sum(sq);
  __shared__ float wsum[4];
  __shared__ float inv_s;
  const int lane = t & 63, wid = t >> 6;
  if (lane == 0) wsum[wid] = sq;
  __syncthreads();
  if (t == 0) inv_s = 1.0f / sqrtf(wsum[0] + wsum[1] + wsum[2] + wsum[3]);
  __syncthreads();
  float inv = inv_s;
#pragma unroll
  for (int k = 0; k < 6; ++k)
    out[b * FD + (k << 8) + t] = v[k] * inv;
}

// --------------------------------------------- pairwise distances via Gram
__global__ __launch_bounds__(256) void dist_k(
    const float* __restrict__ Fn, const float* __restrict__ Gn,
    float* __restrict__ D) {
  const int z = blockIdx.z;
  const float* Bm = z ? Gn : Fn;
  const int i0 = blockIdx.y * 16, j0 = blockIdx.x * 16;
  const int tx = threadIdx.x, ty = threadIdx.y;
  __shared__ float As[16][17], Bs[16][17];
  float acc = 0.0f;
  for (int k0 = 0; k0 < FD; k0 += 16) {
    As[ty][tx] = Fn[(i0 + ty) * FD + k0 + tx];
    Bs[ty][tx] = Bm[(j0 + ty) * FD + k0 + tx];
    __syncthreads();
#pragma unroll
    for (int k = 0; k < 16; ++k) acc = fmaf(As[ty][k], Bs[tx][k], acc);
    __syncthreads();
  }
  float sq = fmaxf(2.0f - 2.0f * acc, 0.0f) + 1e-12f;
  D[z * BATCH * BATCH + (i0 + ty) * BATCH + j0 + tx] = sqrtf(sq);
}

// ---------------------------------------------------------------------------
// Fused tail: per-row partial combine (CE + KL) + hard mining + adversarial
// CE + final weighted sum. One block, 256 threads.
// ---------------------------------------------------------------------------
__global__ __launch_bounds__(256) void final_k(
    const float* __restrict__ P, const float* __restrict__ W,
    const float* __restrict__ D, const float* __restrict__ advl,
    const int* __restrict__ labels, const int* __restrict__ mod,
    const int* __restrict__ epoch, float* __restrict__ out) {
  const int t = threadIdx.x;
  const float i3 = 1.0f / 3.0f;
  __shared__ int slab[BATCH];
  if (t < BATCH) slab[t] = labels[t];

  // --- phase A: combine NPART partials per row -> ce, kl*w ---
  float ce = 0.0f, klw = 0.0f;
#pragma unroll
  for (int k = 0; k < 3; ++k) {
    const int row = t + k * 256;                  // 0..767
    const float* p = P + (size_t)row * NPART * 8;
    float M = p[0], E1 = p[1], E2 = p[2], SX = p[3];
    float SS = p[4], SSL = p[5], SSX = p[6];
    const float xl = p[7];                        // only partial 0 carries it
#pragma unroll
    for (int ch = 1; ch < NPART; ++ch) {
      const float* q = p + ch * 8;
      float mo = q[0];
      float nm = fmaxf(M, mo);
      E1 = E1 * __expf(M - nm) + q[1] * __expf(mo - nm);
      E2 = E2 * __expf((M - nm) * i3) + q[2] * __expf((mo - nm) * i3);
      M = nm;
      SX += q[3]; SS += q[4]; SSL += q[5]; SSX += q[6];
    }
    float logZ  = M + __logf(E1);
    float logZT = M * i3 + __logf(E2);
    ce += 0.9f * (logZ - xl) + 0.1f * (logZ - SX * (1.0f / NCLS));
    float kl = SSL - SSX * i3 + logZT * SS;
    klw += fminf(kl, 5.0f) * W[row];
  }

  // --- phase B: adversarial CE (768 rows of 2 logits) ---
  float adv = 0.0f;
#pragma unroll
  for (int k = 0; k < 3; ++k) {
    const int r = t + k * 256;
    const int b = r & (BATCH - 1);
    float l0 = advl[2 * r], l1 = advl[2 * r + 1];
    float mx = fmaxf(l0, l1);
    float lse = mx + __logf(__expf(l0 - mx) + __expf(l1 - mx));
    adv += lse - (mod[b] ? l1 : l0);
  }

  // --- phase C: hard mining (threads 0..127, one row each) ---
  __syncthreads();                                // slab ready
  float l1s = 0.0f, l2s = 0.0f;
  if (t < BATCH) {
    const int lb = slab[t];
    const float* d1 = D + t * BATCH;
    const float* d2 = D + BATCH * BATCH + t * BATCH;
    float ap1 = -1e30f, an1 = 1e30f, ap2 = -1e30f, an2 = 1e30f;
    int hasp1 = 0, hasn = 0, hasp2 = 0;
    for (int j = 0; j < BATCH; ++j) {
      bool eq = (slab[j] == lb);
      float v1 = d1[j], v2 = d2[j];
      if (eq) {
        hasp2 = 1; ap2 = fmaxf(ap2, v2);
        if (j != t) { hasp1 = 1; ap1 = fmaxf(ap1, v1); }
      } else {
        hasn = 1; an1 = fminf(an1, v1); an2 = fminf(an2, v2);
      }
    }
    float dap1 = hasp1 ? ap1 : 0.0f;
    float dan1 = hasn ? an1 : 1e6f;
    l1s = fmaxf(dap1 - dan1 + 0.3f, 0.0f);
    float dap2 = hasp2 ? ap2 : 0.0f;
    float dan2 = hasn ? an2 : 1e6f;
    l2s = fmaxf(dap2 - dan2 + 0.3f, 0.0f);
  }

  // --- block reduction of all five partial sums ---
  ce  = wave_sum(ce);
  klw = wave_sum(klw);
  adv = wave_sum(adv);
  l1s = wave_sum(l1s);
  l2s = wave_sum(l2s);
  __shared__ float r0[4], r1[4], r2[4], r3[4], r4[4];
  const int lane = t & 63, wid = t >> 6;
  if (lane == 0) { r0[wid]=ce; r1[wid]=klw; r2[wid]=adv; r3[wid]=l1s; r4[wid]=l2s; }
  __syncthreads();
  if (t == 0) {
    float CE  = r0[0] + r0[1] + r0[2] + r0[3];
    float KLW = r1[0] + r1[1] + r1[2] + r1[3];
    float ADV = r2[0] + r2[1] + r2[2] + r2[3];
    float T1  = r3[0] + r3[1] + r3[2] + r3[3];
    float T2  = r4[0] + r4[1] + r4[2] + r4[3];
    float L_id    = CE * (1.0f / NROWS);
    float L_tri   = (T1 + 0.5f * T2) * (1.0f / BATCH);
    float L_graph = (epoch[0] >= 20) ? KLW * (9.0f / 768.0f) : 0.0f;
    float L_adv   = ADV * (1.0f / NROWS);
    out[0] = L_id + L_tri + 0.1f * L_graph + 0.1f * L_adv;
  }
}

extern "C" void kernel_launch(void* const* d_in, const int* in_sizes, int n_in,
                              void* d_out, int out_size, void* d_ws, size_t ws_size,
                              hipStream_t stream) {
  (void)in_sizes; (void)n_in; (void)out_size; (void)ws_size;
  const float* id_logits = (const float*)d_in[0];
  const float* id_feat   = (const float*)d_in[1];
  const float* gray_feat = (const float*)d_in[2];
  const float* soft      = (const float*)d_in[3];
  const float* entw      = (const float*)d_in[4];
  const float* advl      = (const float*)d_in[5];
  const int*   labels    = (const int*)d_in[6];
  const int*   modality  = (const int*)d_in[7];
  const int*   epoch     = (const int*)d_in[8];
  float* out = (float*)d_out;

  float* P  = (float*)d_ws;                 // [768][10][8] wave partials
  float* Fn = P + NROWS * NPART * 8;        // [128][1536]
  float* Gn = Fn + BATCH * FD;              // [128][1536]
  float* D  = Gn + BATCH * FD;              // [2][128][128]

  chunk_k<<<NROWS * NCHUNK, 128, 0, stream>>>(id_logits, soft, labels, P);
  normalize_k<<<256, 256, 0, stream>>>(id_feat, gray_feat, Fn, Gn);
  dist_k<<<dim3(8, 8, 2), dim3(16, 16), 0, stream>>>(Fn, Gn, D);
  final_k<<<1, 256, 0, stream>>>(P, entw, D, advl, labels, modality, epoch, out);
}

// Round 7
// 382.074 us; speedup vs baseline: 1.0414x; 1.0414x over previous
//
#include <hip/hip_runtime.h>

#define NCLS   50000
#define NC4    12500      // NCLS/4
#define BATCH  128
#define PPARTS 6
#define NROWS  768        // PPARTS*BATCH
#define FD     1536       // PPARTS*256
#define NCHUNK 5          // blocks per row
#define CF4    2500       // float4s per block (chunk)
#define KFULL  9          // full unrolled pair-loads per thread (9*256=2304)
#define TAILN  196        // 2500 - 2304 lanes do a 10th pair

typedef float f32x4 __attribute__((ext_vector_type(4)));

__device__ __forceinline__ float wave_sum(float v) {
#pragma unroll
  for (int off = 32; off > 0; off >>= 1) v += __shfl_xor(v, off, 64);
  return v;
}

// ---------------------------------------------------------------------------
// Streaming partial CE+KL stats. Pure-register read engine (m13-copy style):
// each thread issues ALL its loads (up to 10 X + 10 S dwordx4, 320B) before a
// sched_barrier(0) pin, then consumes in order behind compiler-counted vmcnt.
// 256 thr/block, 4 blocks/CU -> 16 waves/CU, ~290KB/CU outstanding demand.
// X is non-temporal (no L3 alloc) so S stays L3-resident (r4-proven win).
// Block combines its 4 waves -> one 8-float partial {m,e1,e2,sx,ss,ssl,ssx,xl}.
// ---------------------------------------------------------------------------
__global__ __launch_bounds__(256, 4) void chunk_k(
    const float* __restrict__ X, const float* __restrict__ S,
    const int* __restrict__ labels, float* __restrict__ P) {
  const int gid = blockIdx.x;
  const int row = gid / NCHUNK;
  const int sp  = gid - row * NCHUNK;
  const int b   = row & (BATCH - 1);
  const int t   = threadIdx.x;
  const size_t base = (size_t)row * NCLS;
  const f32x4* xg4 = (const f32x4*)(X + base) + sp * CF4;
  const f32x4* sg4 = (const f32x4*)(S + base) + sp * CF4;
  const float i3 = 1.0f / 3.0f;

  float xl = 0.0f;
  if (sp == 0 && t == 0) xl = X[base + labels[b]];

  // ---- load phase: issue everything, then pin with sched_barrier ----
  f32x4 xv[10], sv[10];
  xv[9] = (f32x4){0.f, 0.f, 0.f, 0.f};
  sv[9] = (f32x4){1.f, 1.f, 1.f, 1.f};
#pragma unroll
  for (int k = 0; k < KFULL; ++k) {
    xv[k] = __builtin_nontemporal_load(xg4 + t + 256 * k);   // NT: bypass L3
    sv[k] = sg4[t + 256 * k];                                // cached: L3-hit
  }
  const bool tail = t < TAILN;
  if (tail) {
    xv[9] = __builtin_nontemporal_load(xg4 + t + 256 * 9);
    sv[9] = sg4[t + 256 * 9];
  }
  __builtin_amdgcn_sched_barrier(0);   // loads stay above; uses stay below

  // ---- compute phase: online max-rescaled accumulators ----
  float m = -1e30f, e1 = 0.0f, e2 = 0.0f;
  float sx = 0.0f, ss = 0.0f, ssl = 0.0f, ssx = 0.0f;

  auto proc = [&](f32x4 xq, f32x4 sq) {
    const float x0 = xq.x, x1 = xq.y, x2 = xq.z, x3 = xq.w;
    const float s0 = sq.x, s1 = sq.y, s2 = sq.z, s3 = sq.w;
    const float mx = fmaxf(fmaxf(x0, x1), fmaxf(x2, x3));
    const float nm = fmaxf(m, mx);
    const float r3 = __expf((m - nm) * i3);   // exp((m-nm)/3)
    const float r  = r3 * r3 * r3;            // exp(m-nm)
    const float u0 = __expf((x0 - nm) * i3);
    const float u1 = __expf((x1 - nm) * i3);
    const float u2 = __expf((x2 - nm) * i3);
    const float u3 = __expf((x3 - nm) * i3);
    e2 = e2 * r3 + ((u0 + u1) + (u2 + u3));
    float q0 = u0 * u0, q1 = u1 * u1, q2 = u2 * u2, q3 = u3 * u3;
    e1 = e1 * r + ((q0 * u0 + q1 * u1) + (q2 * u2 + q3 * u3));
    m = nm;
    sx += ((x0 + x1) + (x2 + x3));
    ss += ((s0 + s1) + (s2 + s3));
    ssl = fmaf(s0, __logf(s0), ssl);
    ssl = fmaf(s1, __logf(s1), ssl);
    ssl = fmaf(s2, __logf(s2), ssl);
    ssl = fmaf(s3, __logf(s3), ssl);
    ssx = fmaf(s0, x0, ssx);
    ssx = fmaf(s1, x1, ssx);
    ssx = fmaf(s2, x2, ssx);
    ssx = fmaf(s3, x3, ssx);
  };

#pragma unroll
  for (int k = 0; k < KFULL; ++k) proc(xv[k], sv[k]);
  if (tail) proc(xv[9], sv[9]);

  // ---- wave reduction with max-rescale ----
#pragma unroll
  for (int off = 32; off > 0; off >>= 1) {
    float mo  = __shfl_xor(m, off, 64);
    float e1o = __shfl_xor(e1, off, 64);
    float e2o = __shfl_xor(e2, off, 64);
    float nm = fmaxf(m, mo);
    e1 = e1 * __expf(m - nm) + e1o * __expf(mo - nm);
    e2 = e2 * __expf((m - nm) * i3) + e2o * __expf((mo - nm) * i3);
    m = nm;
    sx  += __shfl_xor(sx, off, 64);
    ss  += __shfl_xor(ss, off, 64);
    ssl += __shfl_xor(ssl, off, 64);
    ssx += __shfl_xor(ssx, off, 64);
  }

  // ---- cross-wave combine (4 waves) ----
  __shared__ float rm[4], re1[4], re2[4], rsx[4], rss[4], rssl[4], rssx[4];
  const int lane = t & 63, wid = t >> 6;
  if (lane == 0) {
    rm[wid] = m; re1[wid] = e1; re2[wid] = e2;
    rsx[wid] = sx; rss[wid] = ss; rssl[wid] = ssl; rssx[wid] = ssx;
  }
  __syncthreads();
  if (t == 0) {
    float M = rm[0], E1 = re1[0], E2 = re2[0];
#pragma unroll
    for (int wv = 1; wv < 4; ++wv) {
      float nm = fmaxf(M, rm[wv]);
      E1 = E1 * __expf(M - nm) + re1[wv] * __expf(rm[wv] - nm);
      E2 = E2 * __expf((M - nm) * i3) + re2[wv] * __expf((rm[wv] - nm) * i3);
      M = nm;
    }
    float4* o = (float4*)(P + (size_t)gid * 8);
    o[0] = make_float4(M, E1, E2, rsx[0] + rsx[1] + rsx[2] + rsx[3]);
    o[1] = make_float4(rss[0] + rss[1] + rss[2] + rss[3],
                       rssl[0] + rssl[1] + rssl[2] + rssl[3],
                       rssx[0] + rssx[1] + rssx[2] + rssx[3], xl);
  }
}

// ---------------------------------------------- normalize concat features
__global__ __launch_bounds__(256) void normalize_k(
    const float* __restrict__ idf, const float* __restrict__ grayf,
    float* __restrict__ Fn, float* __restrict__ Gn) {
  const int src = blockIdx.x >> 7;
  const int b = blockIdx.x & (BATCH - 1);
  const int t = threadIdx.x;
  const float* in = src ? grayf : idf;
  float* out = src ? Gn : Fn;

  float v[6];
  float sq = 0.0f;
#pragma unroll
  for (int k = 0; k < 6; ++k) {
    v[k] = in[((k * BATCH + b) << 8) + t];
    sq = fmaf(v[k], v[k], sq);
  }
  sq = wave_sum(sq);
  __shared__ float wsum[4];
  __shared__ float inv_s;
  const int lane = t & 63, wid = t >> 6;
  if (lane == 0) wsum[wid] = sq;
  __syncthreads();
  if (t == 0) inv_s = 1.0f / sqrtf(wsum[0] + wsum[1] + wsum[2] + wsum[3]);
  __syncthreads();
  float inv = inv_s;
#pragma unroll
  for (int k = 0; k < 6; ++k)
    out[b * FD + (k << 8) + t] = v[k] * inv;
}

// --------------------------------------------- pairwise distances via Gram
__global__ __launch_bounds__(256) void dist_k(
    const float* __restrict__ Fn, const float* __restrict__ Gn,
    float* __restrict__ D) {
  const int z = blockIdx.z;
  const float* Bm = z ? Gn : Fn;
  const int i0 = blockIdx.y * 16, j0 = blockIdx.x * 16;
  const int tx = threadIdx.x, ty = threadIdx.y;
  __shared__ float As[16][17], Bs[16][17];
  float acc = 0.0f;
  for (int k0 = 0; k0 < FD; k0 += 16) {
    As[ty][tx] = Fn[(i0 + ty) * FD + k0 + tx];
    Bs[ty][tx] = Bm[(j0 + ty) * FD + k0 + tx];
    __syncthreads();
#pragma unroll
    for (int k = 0; k < 16; ++k) acc = fmaf(As[ty][k], Bs[tx][k], acc);
    __syncthreads();
  }
  float sq = fmaxf(2.0f - 2.0f * acc, 0.0f) + 1e-12f;
  D[z * BATCH * BATCH + (i0 + ty) * BATCH + j0 + tx] = sqrtf(sq);
}

// ---------------------------------------------------------------------------
// Fused tail: per-row chunk combine (CE + KL) + hard mining + adversarial CE
// + final weighted sum. One block, 256 threads.
// ---------------------------------------------------------------------------
__global__ __launch_bounds__(256) void final_k(
    const float* __restrict__ P, const float* __restrict__ W,
    const float* __restrict__ D, const float* __restrict__ advl,
    const int* __restrict__ labels, const int* __restrict__ mod,
    const int* __restrict__ epoch, float* __restrict__ out) {
  const int t = threadIdx.x;
  const float i3 = 1.0f / 3.0f;
  __shared__ int slab[BATCH];
  if (t < BATCH) slab[t] = labels[t];

  // --- phase A: combine NCHUNK partials per row -> ce, kl*w ---
  float ce = 0.0f, klw = 0.0f;
#pragma unroll
  for (int k = 0; k < 3; ++k) {
    const int row = t + k * 256;                  // 0..767
    const float* p = P + (size_t)row * NCHUNK * 8;
    float M = p[0], E1 = p[1], E2 = p[2], SX = p[3];
    float SS = p[4], SSL = p[5], SSX = p[6];
    const float xl = p[7];                        // only chunk 0 carries it
#pragma unroll
    for (int ch = 1; ch < NCHUNK; ++ch) {
      const float* q = p + ch * 8;
      float mo = q[0];
      float nm = fmaxf(M, mo);
      E1 = E1 * __expf(M - nm) + q[1] * __expf(mo - nm);
      E2 = E2 * __expf((M - nm) * i3) + q[2] * __expf((mo - nm) * i3);
      M = nm;
      SX += q[3]; SS += q[4]; SSL += q[5]; SSX += q[6];
    }
    float logZ  = M + __logf(E1);
    float logZT = M * i3 + __logf(E2);
    ce += 0.9f * (logZ - xl) + 0.1f * (logZ - SX * (1.0f / NCLS));
    float kl = SSL - SSX * i3 + logZT * SS;
    klw += fminf(kl, 5.0f) * W[row];
  }

  // --- phase B: adversarial CE (768 rows of 2 logits) ---
  float adv = 0.0f;
#pragma unroll
  for (int k = 0; k < 3; ++k) {
    const int r = t + k * 256;
    const int b = r & (BATCH - 1);
    float l0 = advl[2 * r], l1 = advl[2 * r + 1];
    float mx = fmaxf(l0, l1);
    float lse = mx + __logf(__expf(l0 - mx) + __expf(l1 - mx));
    adv += lse - (mod[b] ? l1 : l0);
  }

  // --- phase C: hard mining (threads 0..127, one row each) ---
  __syncthreads();                                // slab ready
  float l1s = 0.0f, l2s = 0.0f;
  if (t < BATCH) {
    const int lb = slab[t];
    const float* d1 = D + t * BATCH;
    const float* d2 = D + BATCH * BATCH + t * BATCH;
    float ap1 = -1e30f, an1 = 1e30f, ap2 = -1e30f, an2 = 1e30f;
    int hasp1 = 0, hasn = 0, hasp2 = 0;
    for (int j = 0; j < BATCH; ++j) {
      bool eq = (slab[j] == lb);
      float v1 = d1[j], v2 = d2[j];
      if (eq) {
        hasp2 = 1; ap2 = fmaxf(ap2, v2);
        if (j != t) { hasp1 = 1; ap1 = fmaxf(ap1, v1); }
      } else {
        hasn = 1; an1 = fminf(an1, v1); an2 = fminf(an2, v2);
      }
    }
    float dap1 = hasp1 ? ap1 : 0.0f;
    float dan1 = hasn ? an1 : 1e6f;
    l1s = fmaxf(dap1 - dan1 + 0.3f, 0.0f);
    float dap2 = hasp2 ? ap2 : 0.0f;
    float dan2 = hasn ? an2 : 1e6f;
    l2s = fmaxf(dap2 - dan2 + 0.3f, 0.0f);
  }

  // --- block reduction of all five partial sums ---
  ce  = wave_sum(ce);
  klw = wave_sum(klw);
  adv = wave_sum(adv);
  l1s = wave_sum(l1s);
  l2s = wave_sum(l2s);
  __shared__ float r0[4], r1[4], r2[4], r3[4], r4[4];
  const int lane = t & 63, wid = t >> 6;
  if (lane == 0) { r0[wid]=ce; r1[wid]=klw; r2[wid]=adv; r3[wid]=l1s; r4[wid]=l2s; }
  __syncthreads();
  if (t == 0) {
    float CE  = r0[0] + r0[1] + r0[2] + r0[3];
    float KLW = r1[0] + r1[1] + r1[2] + r1[3];
    float ADV = r2[0] + r2[1] + r2[2] + r2[3];
    float T1  = r3[0] + r3[1] + r3[2] + r3[3];
    float T2  = r4[0] + r4[1] + r4[2] + r4[3];
    float L_id    = CE * (1.0f / NROWS);
    float L_tri   = (T1 + 0.5f * T2) * (1.0f / BATCH);
    float L_graph = (epoch[0] >= 20) ? KLW * (9.0f / 768.0f) : 0.0f;
    float L_adv   = ADV * (1.0f / NROWS);
    out[0] = L_id + L_tri + 0.1f * L_graph + 0.1f * L_adv;
  }
}

extern "C" void kernel_launch(void* const* d_in, const int* in_sizes, int n_in,
                              void* d_out, int out_size, void* d_ws, size_t ws_size,
                              hipStream_t stream) {
  (void)in_sizes; (void)n_in; (void)out_size; (void)ws_size;
  const float* id_logits = (const float*)d_in[0];
  const float* id_feat   = (const float*)d_in[1];
  const float* gray_feat = (const float*)d_in[2];
  const float* soft      = (const float*)d_in[3];
  const float* entw      = (const float*)d_in[4];
  const float* advl      = (const float*)d_in[5];
  const int*   labels    = (const int*)d_in[6];
  const int*   modality  = (const int*)d_in[7];
  const int*   epoch     = (const int*)d_in[8];
  float* out = (float*)d_out;

  float* P  = (float*)d_ws;                 // [768][5][8] chunk partials
  float* Fn = P + NROWS * NCHUNK * 8;       // [128][1536]
  float* Gn = Fn + BATCH * FD;              // [128][1536]
  float* D  = Gn + BATCH * FD;              // [2][128][128]

  chunk_k<<<NROWS * NCHUNK, 256, 0, stream>>>(id_logits, soft, labels, P);
  normalize_k<<<256, 256, 0, stream>>>(id_feat, gray_feat, Fn, Gn);
  dist_k<<<dim3(8, 8, 2), dim3(16, 16), 0, stream>>>(Fn, Gn, D);
  final_k<<<1, 256, 0, stream>>>(P, entw, D, advl, labels, modality, epoch, out);
}